// Round 10
// baseline (846.866 us; speedup 1.0000x reference)
//
#include <hip/hip_runtime.h>
#include <hip/hip_bf16.h>
#include <cstdint>

typedef __hip_bfloat16 bf16;
typedef __hip_bfloat162 bf162;
typedef __bf16 bf16x8 __attribute__((ext_vector_type(8)));
typedef float f32x4 __attribute__((ext_vector_type(4)));

// ---------- dtype detection ----------
__global__ void detect_kernel(const unsigned short* __restrict__ xr, int* __restrict__ flag) {
  if (threadIdx.x == 0 && blockIdx.x == 0) {
    int pass = 0;
    for (int i = 0; i < 64; ++i) {
      unsigned short h = xr[2 * i];
      int e = (h >> 7) & 0xFF;
      if (e >= 110 && e <= 140) pass++;
    }
    *flag = (pass >= 32) ? 1 : 0;
  }
}

// ---------- batched weight conversion: 12 tensors in one launch ----------
struct CvtDesc {
  const void* src;
  void* dst;
  int n, fi, fo, mode;  // mode 1: transpose [fi][fo] -> bf16 [fo][fi]; mode 0: flat fp32
};
struct CvtAll { CvtDesc d[12]; };

__global__ void convert_all_kernel(CvtAll all, const int* __restrict__ flag) {
  CvtDesc dd = all.d[blockIdx.y];
  int isbf = *flag;
  for (int i = blockIdx.x * blockDim.x + threadIdx.x; i < dd.n; i += gridDim.x * blockDim.x) {
    float v = isbf ? __bfloat162float(((const bf16*)dd.src)[i]) : ((const float*)dd.src)[i];
    if (dd.mode) {
      int k = i / dd.fo, nn = i - k * dd.fo;
      ((__bf16*)dd.dst)[(size_t)nn * dd.fi + k] = (__bf16)v;
    } else {
      ((float*)dd.dst)[i] = v;
    }
  }
}

// ---------- graph preprocessing ----------

__global__ void count_kernel(const int* __restrict__ dst, int* __restrict__ deg, int E) {
  int i = blockIdx.x * blockDim.x + threadIdx.x;
  if (i < E) atomicAdd(&deg[dst[i]], 1);
}

// scan_block also emits dinv = rsqrt(deg+1) (it reads deg anyway; saves a launch)
__global__ void scan_block_kernel(const int* __restrict__ counts, int* __restrict__ excl,
                                  int* __restrict__ bsum, float* __restrict__ dinv, int n) {
  __shared__ int sd[1024];
  int t = threadIdx.x;
  int i = blockIdx.x * 1024 + t;
  int v = (i < n) ? counts[i] : 0;
  if (i < n) dinv[i] = rsqrtf((float)(v + 1));  // +1 self-loop
  sd[t] = v;
  __syncthreads();
  for (int off = 1; off < 1024; off <<= 1) {
    int x = (t >= off) ? sd[t - off] : 0;
    __syncthreads();
    sd[t] += x;
    __syncthreads();
  }
  if (i < n) excl[i] = sd[t] - v;
  if (t == 1023) bsum[blockIdx.x] = sd[1023];
}

__global__ void scan_sums_kernel(int* __restrict__ bsum, int nb, int* __restrict__ row_ptr, int n) {
  __shared__ int sd[1024];
  int t = threadIdx.x;
  int v = (t < nb) ? bsum[t] : 0;
  sd[t] = v;
  __syncthreads();
  for (int off = 1; off < 1024; off <<= 1) {
    int x = (t >= off) ? sd[t - off] : 0;
    __syncthreads();
    sd[t] += x;
    __syncthreads();
  }
  if (t < nb) bsum[t] = sd[t] - v;
  if (t == 1023) row_ptr[n] = sd[1023];
}

__global__ void scan_add_kernel(int* __restrict__ excl, const int* __restrict__ bsum, int n) {
  int i = blockIdx.x * blockDim.x + threadIdx.x;
  if (i < n) excl[i] += bsum[i >> 10];
}

// fill claims slots by counting deg back down (deg is dead after scan+dinv).
// NOTE (round-9 profile): 131us, WRITE_SIZE=107MB for a 6.4MB col array --
// 16x write amplification from random 4B scatter. Known target; untouched
// this round (one major change per round).
__global__ void fill_kernel(const int* __restrict__ src, const int* __restrict__ dst,
                            const int* __restrict__ row_ptr, int* __restrict__ deg,
                            int* __restrict__ col, int E) {
  int i = blockIdx.x * blockDim.x + threadIdx.x;
  if (i < E) {
    int d = dst[i];
    int k = atomicSub(&deg[d], 1) - 1;
    col[row_ptr[d] + k] = src[i];
  }
}

// ---------- async global->LDS helper (16B, literal size per guide) ----------
__device__ __forceinline__ void gload_lds16(const void* g, void* l) {
  __builtin_amdgcn_global_load_lds(
      (const __attribute__((address_space(1))) void*)g,
      (__attribute__((address_space(3))) void*)l, 16, 0, 0);
}

// ---------- conv0 GEMM (K=512): contiguous-read persistent kernel ----------
// THEORY UNDER TEST (round-10): all prior structures load A as scattered
// 64-128B segments per wave-instruction (8 rows x 128B at 1KB stride) and
// all plateau at ~1 TB/s HBM; contiguous per-wave 1KB reads measure 6.3TB/s
// (m13) and the harness fill writes at 6.9. Fix: each wave-instruction reads
// ONE FULL 1KB x-row. Contiguous DMA dest can't be swizzled (rule #21) and
// linear LDS would 16-way-conflict on the MFMA reads, so REG-STAGE (m151/HK):
// global_load_dwordx4 contiguous -> regs -> XOR-swizzled ds_write_b128.
// Structure: persistent grid (256 blocks = 1/CU), 64-row x K=512 panels,
// double-buffered in 128KB LDS, T14 async split: issue next panel's 16
// contiguous loads -> compute current (B reg-dbuf from L2-hot Bt) ->
// ds_write (compiler inserts vmcnt) -> barrier. 4 waves: 2x2 grid, each
// wave 32 rows x 64 cols = acc[2][4]. C/D layout col=lane&15, row=quad*4+reg.
// Swizzle byte ^= (row&7)<<4 on both ds_write and ds_read: write is
// row-uniform per instr (conflict-free); read spreads 16 rows to 2-way (free).

template <int ADUAL>
__global__ __launch_bounds__(256) void gemm512_contig_kernel(
    const void* __restrict__ Ain, const __bf16* __restrict__ Bt,
    const float* __restrict__ bias, bf16* __restrict__ C,
    int M, const float* __restrict__ rowscale, int do_relu,
    const int* __restrict__ flag) {
  __shared__ __align__(16) __bf16 Ap[2][64 * 512];  // 64KB per buffer
  const int abf = ADUAL ? flag[0] : 1;
  int t = threadIdx.x;
  int wave = t >> 6, lane = t & 63;
  int l15 = lane & 15, quad = lane >> 4;
  int wm = wave >> 1, wn = wave & 1;
  const __bf16* Ab = (const __bf16*)Ain;
  const float* Af = (const float*)Ain;
  const int G = gridDim.x;
  const int npan = (M + 63) >> 6;

  bf16x8 v[16];  // staged panel rows (wave covers rows j*4+wave, j=0..15)

  auto ldpanel = [&](int p) {
#pragma unroll
    for (int j = 0; j < 16; ++j) {
      int gr = p * 64 + j * 4 + wave;
      if (gr >= M) gr = M - 1;  // dup loads harmless; masked at store
      if (abf) {
        v[j] = *(const bf16x8*)(Ab + (size_t)gr * 512 + lane * 8);  // 1KB/instr contiguous
      } else {
        const float* pr = Af + (size_t)gr * 512 + lane * 8;
        f32x4 a = *(const f32x4*)pr;
        f32x4 b = *(const f32x4*)(pr + 4);
#pragma unroll
        for (int k = 0; k < 4; ++k) {
          v[j][k] = (__bf16)a[k];
          v[j][4 + k] = (__bf16)b[k];
        }
      }
    }
  };

  auto wrpanel = [&](int buf) {
#pragma unroll
    for (int j = 0; j < 16; ++j) {
      int r = j * 4 + wave;
      int byte = (r << 10) + lane * 16;
      byte ^= (r & 7) << 4;  // row-uniform XOR: conflict-free write
      *(bf16x8*)((char*)&Ap[buf][0] + byte) = v[j];
    }
  };

  int p = blockIdx.x;
  if (p >= npan) return;  // block-uniform; no divergent-barrier hazard

  ldpanel(p);
  wrpanel(0);
  __syncthreads();
  int buf = 0;

  while (true) {
    int pn = p + G;
    bool more = pn < npan;
    if (more) ldpanel(pn);  // issue contiguous loads EARLY (T14); consumed at wrpanel

    // ---- compute panel p from Ap[buf] ----
    f32x4 acc[2][4];
#pragma unroll
    for (int mt = 0; mt < 2; ++mt)
#pragma unroll
      for (int nt = 0; nt < 4; ++nt) acc[mt][nt] = (f32x4){0.f, 0.f, 0.f, 0.f};

    bf16x8 avA[2], avB[2], bA[4], bB[4];
    auto ldA = [&](int c, bf16x8 (&av)[2]) {
#pragma unroll
      for (int mt = 0; mt < 2; ++mt) {
        int row = wm * 32 + mt * 16 + l15;
        int byte = (row << 10) + c * 64 + quad * 16;
        byte ^= (row & 7) << 4;
        av[mt] = *(const bf16x8*)((const char*)&Ap[buf][0] + byte);
      }
    };
    auto ldB = [&](int c, bf16x8 (&bv)[4]) {
      int ko = c * 32 + quad * 8;
#pragma unroll
      for (int nt = 0; nt < 4; ++nt)
        bv[nt] = *(const bf16x8*)(Bt + (size_t)(wn * 64 + nt * 16 + l15) * 512 + ko);
    };
    auto mm = [&](const bf16x8 (&av)[2], const bf16x8 (&bv)[4]) {
#pragma unroll
      for (int mt = 0; mt < 2; ++mt)
#pragma unroll
        for (int nt = 0; nt < 4; ++nt)
          acc[mt][nt] =
              __builtin_amdgcn_mfma_f32_16x16x32_bf16(av[mt], bv[nt], acc[mt][nt], 0, 0, 0);
    };

    ldA(0, avA);
    ldB(0, bA);
#pragma unroll
    for (int c = 0; c < 16; c += 2) {
      if (c + 1 < 16) {
        ldA(c + 1, avB);
        ldB(c + 1, bB);
      }
      mm(avA, bA);
      if (c + 2 < 16) {
        ldA(c + 2, avA);
        ldB(c + 2, bA);
      }
      if (c + 1 < 16) mm(avB, bB);
    }

    // ---- epilogue for panel p ----
#pragma unroll
    for (int mt = 0; mt < 2; ++mt) {
      int r0 = p * 64 + wm * 32 + mt * 16 + quad * 4;
#pragma unroll
      for (int nt = 0; nt < 4; ++nt) {
        int c = wn * 64 + nt * 16 + l15;
        float bs = bias[c];
#pragma unroll
        for (int i = 0; i < 4; ++i) {
          int r = r0 + i;
          if (r < M) {
            float val = acc[mt][nt][i] + bs;
            if (rowscale) val *= rowscale[r];
            if (do_relu) val = fmaxf(val, 0.f);
            C[(size_t)r * 128 + c] = __float2bfloat16(val);
          }
        }
      }
    }

    if (!more) break;
    __syncthreads();      // all reads of buf^1's predecessor done
    wrpanel(buf ^ 1);     // compiler inserts vmcnt for v[] loads
    __syncthreads();      // panel pn visible to all waves
    buf ^= 1;
    p = pn;
  }
}

// ---------- MFMA GEMM (K=128): round-8 proven A+B LDS staging, counted vmcnt ----------
// Round-9 falsified A-only staging (119->131us): B-from-L2 per-chunk exposes
// L2 latency and the occupancy gain never materialized. Reverted to the
// measured-best round-8 structure: both operands DMA-staged, vmcnt(8)
// counted wait (T4), raw barriers, sched_barrier fences (rule #18).
// XOR swizzle slot^(row&7) as pre-swizzled GLOBAL source + swizzled read,
// LDS dest linear (rule #21). 64KB LDS -> 2 blocks/CU.

template <int K, int ADUAL>
__global__ __launch_bounds__(256) void gemm_mfma_kernel(
    const void* __restrict__ Ain, const __bf16* __restrict__ Bt,
    const float* __restrict__ bias, bf16* __restrict__ C,
    int M, const float* __restrict__ rowscale, int do_relu,
    const int* __restrict__ flag) {
  constexpr int BK = 64;
  constexpr int NT = K / BK;
  __shared__ __align__(16) __bf16 As[2][128 * BK];
  __shared__ __align__(16) __bf16 Bs[2][128 * BK];

  const int abf = ADUAL ? flag[0] : 1;
  int t = threadIdx.x;
  int wave = t >> 6, lane = t & 63;
  int l15 = lane & 15, quad = lane >> 4;
  int wm = wave >> 1, wn = wave & 1;
  int rowbase = blockIdx.x * 128;
  const __bf16* Ab = (const __bf16*)Ain;
  const float* Af = (const float*)Ain;

  int srow = t >> 3;
  int sslot = t & 7;
  int xslot = sslot ^ (srow & 7);

  int sArow[4];
#pragma unroll
  for (int i = 0; i < 4; ++i) {
    int r = rowbase + i * 32 + srow;
    sArow[i] = (r < M) ? r : (M - 1);
  }

  f32x4 acc[4][4];
#pragma unroll
  for (int mt = 0; mt < 4; ++mt)
#pragma unroll
    for (int nt = 0; nt < 4; ++nt) acc[mt][nt] = (f32x4){0.f, 0.f, 0.f, 0.f};

  auto stage = [&](int kt, int buf) {
    int kbase = kt * BK + xslot * 8;
    if (abf) {
#pragma unroll
      for (int i = 0; i < 4; ++i)
        gload_lds16(Ab + (size_t)sArow[i] * K + kbase, &As[buf][t * 8 + i * 2048]);
    } else {
#pragma unroll
      for (int i = 0; i < 4; ++i) {
        const float* p = Af + (size_t)sArow[i] * K + kbase;
        bf16x8 v;
#pragma unroll
        for (int j = 0; j < 8; ++j) v[j] = (__bf16)p[j];
        *(bf16x8*)&As[buf][t * 8 + i * 2048] = v;
      }
    }
#pragma unroll
    for (int i = 0; i < 4; ++i)
      gload_lds16(Bt + (size_t)(i * 32 + srow) * K + kbase, &Bs[buf][t * 8 + i * 2048]);
  };

  auto compute = [&](int buf) {
#pragma unroll
    for (int c = 0; c < 2; ++c) {
      bf16x8 av[4], bv[4];
#pragma unroll
      for (int mt = 0; mt < 4; ++mt) {
        int row = wm * 64 + mt * 16 + l15;
        int slot = (c * 4 + quad) ^ (row & 7);
        av[mt] = *(const bf16x8*)&As[buf][row * BK + slot * 8];
      }
#pragma unroll
      for (int nt = 0; nt < 4; ++nt) {
        int row = wn * 64 + nt * 16 + l15;
        int slot = (c * 4 + quad) ^ (row & 7);
        bv[nt] = *(const bf16x8*)&Bs[buf][row * BK + slot * 8];
      }
#pragma unroll
      for (int mt = 0; mt < 4; ++mt)
#pragma unroll
        for (int nt = 0; nt < 4; ++nt)
          acc[mt][nt] =
              __builtin_amdgcn_mfma_f32_16x16x32_bf16(av[mt], bv[nt], acc[mt][nt], 0, 0, 0);
    }
  };

  stage(0, 0);
  if (abf) {
#pragma unroll
    for (int kt = 0; kt < NT; ++kt) {
      int cur = kt & 1;
      if (kt + 1 < NT) {
        stage(kt + 1, cur ^ 1);
        asm volatile("s_waitcnt vmcnt(8)" ::: "memory");
      } else {
        asm volatile("s_waitcnt vmcnt(0)" ::: "memory");
      }
      __builtin_amdgcn_sched_barrier(0);
      __builtin_amdgcn_s_barrier();
      __builtin_amdgcn_sched_barrier(0);
      compute(cur);
      __builtin_amdgcn_sched_barrier(0);
      __builtin_amdgcn_s_barrier();
    }
  } else {
    __syncthreads();
#pragma unroll
    for (int kt = 0; kt < NT; ++kt) {
      int cur = kt & 1;
      if (kt + 1 < NT) stage(kt + 1, cur ^ 1);
      compute(cur);
      __syncthreads();
    }
  }

#pragma unroll
  for (int mt = 0; mt < 4; ++mt) {
    int r0 = rowbase + wm * 64 + mt * 16 + quad * 4;
#pragma unroll
    for (int nt = 0; nt < 4; ++nt) {
      int c = wn * 64 + nt * 16 + l15;
      float bs = bias[c];
#pragma unroll
      for (int i = 0; i < 4; ++i) {
        int r = r0 + i;
        if (r < M) {
          float v = acc[mt][nt][i] + bs;
          if (rowscale) v *= rowscale[r];
          if (do_relu) v = fmaxf(v, 0.f);
          C[(size_t)r * 128 + c] = __float2bfloat16(v);
        }
      }
    }
  }
}

// ---------- gather: y[d] = relu(dinv[d]*(g[d] + sum_{s in CSR[d]} g[s])) ----------
// 8-wide batches + next-batch col prefetch; round-7 showed fabric/BW-bound.

__global__ __launch_bounds__(256) void gather_kernel(
    const bf16* __restrict__ g, const int* __restrict__ row_ptr, const int* __restrict__ col,
    const float* __restrict__ dinv, bf16* __restrict__ y, int n) {
  int wave = threadIdx.x >> 6;
  int lane = threadIdx.x & 63;
  int node = blockIdx.x * 4 + wave;
  if (node >= n) return;
  const bf162* gp = (const bf162*)g;
  bf162 sv = gp[(size_t)node * 64 + lane];
  float ax = __bfloat162float(sv.x), ay = __bfloat162float(sv.y);
  float bx = 0.f, by = 0.f;
  int beg = row_ptr[node], end = row_ptr[node + 1];

  if (beg < end) {
    int sc[8], sn[8];
    float mc[8], mn[8];
#pragma unroll
    for (int j = 0; j < 8; ++j) {
      int ee = beg + j;
      bool ok = ee < end;
      sc[j] = col[ok ? ee : beg];
      mc[j] = ok ? 1.f : 0.f;
    }
    for (int e = beg; e < end; e += 8) {
      bf162 v[8];
#pragma unroll
      for (int j = 0; j < 8; ++j) v[j] = gp[(size_t)sc[j] * 64 + lane];
      int e2 = e + 8;
      bool more = e2 < end;
      if (more) {
#pragma unroll
        for (int j = 0; j < 8; ++j) {
          int ee = e2 + j;
          bool ok = ee < end;
          sn[j] = col[ok ? ee : beg];
          mn[j] = ok ? 1.f : 0.f;
        }
      }
#pragma unroll
      for (int j = 0; j < 8; j += 2) {
        ax = fmaf(mc[j], __bfloat162float(v[j].x), ax);
        ay = fmaf(mc[j], __bfloat162float(v[j].y), ay);
        bx = fmaf(mc[j + 1], __bfloat162float(v[j + 1].x), bx);
        by = fmaf(mc[j + 1], __bfloat162float(v[j + 1].y), by);
      }
      if (more) {
#pragma unroll
        for (int j = 0; j < 8; ++j) {
          sc[j] = sn[j];
          mc[j] = mn[j];
        }
      }
    }
  }
  float dv = dinv[node];
  float ox = fmaxf((ax + bx) * dv, 0.f);
  float oy = fmaxf((ay + by) * dv, 0.f);
  bf162 o;
  o.x = __float2bfloat16(ox);
  o.y = __float2bfloat16(oy);
  ((bf162*)y)[(size_t)node * 64 + lane] = o;
}

// ---------- fused FC chain: out = log_softmax(relu(relu(y@W1+b1)@W2+b2)@W3+b3) ----------

__global__ __launch_bounds__(256) void fc_chain_kernel(
    const bf16* __restrict__ yin, const __bf16* __restrict__ W1t,
    const float* __restrict__ b1, const __bf16* __restrict__ W2t,
    const float* __restrict__ b2, const __bf16* __restrict__ W3t,
    const float* __restrict__ b3, void* __restrict__ out, int M,
    const int* __restrict__ flag) {
  constexpr int LDH = 136;
  __shared__ __align__(16) __bf16 h1[128 * LDH];
  __shared__ __align__(16) __bf16 h2[128 * LDH];
  const int isbf = flag[0];
  int t = threadIdx.x;
  int wave = t >> 6, lane = t & 63;
  int l15 = lane & 15, quad = lane >> 4;
  int wm = wave >> 1, wn = wave & 1;
  int rowbase = blockIdx.x * 128;

  f32x4 acc[4][4];
  bf16x8 aA[4], bA[4], aB[4], bB[4];

  auto zacc = [&]() {
#pragma unroll
    for (int mt = 0; mt < 4; ++mt)
#pragma unroll
      for (int nt = 0; nt < 4; ++nt) acc[mt][nt] = (f32x4){0.f, 0.f, 0.f, 0.f};
  };
  auto mfma16 = [&](const bf16x8 (&av)[4], const bf16x8 (&bv)[4]) {
#pragma unroll
    for (int mt = 0; mt < 4; ++mt)
#pragma unroll
      for (int nt = 0; nt < 4; ++nt)
        acc[mt][nt] =
            __builtin_amdgcn_mfma_f32_16x16x32_bf16(av[mt], bv[nt], acc[mt][nt], 0, 0, 0);
  };

  int arow[4];
#pragma unroll
  for (int mt = 0; mt < 4; ++mt) {
    int r = rowbase + wm * 64 + mt * 16 + l15;
    arow[mt] = (r < M) ? r : (M - 1);
  }
  auto ld1 = [&](int kc, bf16x8 (&av)[4], bf16x8 (&bv)[4]) {
    int ko = kc + quad * 8;
#pragma unroll
    for (int mt = 0; mt < 4; ++mt)
      av[mt] = *(const bf16x8*)(yin + (size_t)arow[mt] * 128 + ko);
#pragma unroll
    for (int nt = 0; nt < 4; ++nt)
      bv[nt] = *(const bf16x8*)(W1t + (size_t)(wn * 64 + nt * 16 + l15) * 128 + ko);
  };
  zacc();
  ld1(0, aA, bA);
  ld1(32, aB, bB);
  mfma16(aA, bA);
  ld1(64, aA, bA);
  mfma16(aB, bB);
  ld1(96, aB, bB);
  mfma16(aA, bA);
  mfma16(aB, bB);
#pragma unroll
  for (int mt = 0; mt < 4; ++mt) {
    int rl0 = wm * 64 + mt * 16 + quad * 4;
#pragma unroll
    for (int nt = 0; nt < 4; ++nt) {
      int c = wn * 64 + nt * 16 + l15;
      float bs = b1[c];
#pragma unroll
      for (int i = 0; i < 4; ++i)
        h1[(rl0 + i) * LDH + c] = (__bf16)fmaxf(acc[mt][nt][i] + bs, 0.f);
    }
  }
  __syncthreads();

  auto ld2 = [&](int kc, bf16x8 (&av)[4], bf16x8 (&bv)[4]) {
    int ko = kc + quad * 8;
#pragma unroll
    for (int mt = 0; mt < 4; ++mt)
      av[mt] = *(const bf16x8*)&h1[(wm * 64 + mt * 16 + l15) * LDH + ko];
#pragma unroll
    for (int nt = 0; nt < 4; ++nt)
      bv[nt] = *(const bf16x8*)(W2t + (size_t)(wn * 64 + nt * 16 + l15) * 128 + ko);
  };
  zacc();
  ld2(0, aA, bA);
  ld2(32, aB, bB);
  mfma16(aA, bA);
  ld2(64, aA, bA);
  mfma16(aB, bB);
  ld2(96, aB, bB);
  mfma16(aA, bA);
  mfma16(aB, bB);
#pragma unroll
  for (int mt = 0; mt < 4; ++mt) {
    int rl0 = wm * 64 + mt * 16 + quad * 4;
#pragma unroll
    for (int nt = 0; nt < 4; ++nt) {
      int c = wn * 64 + nt * 16 + l15;
      float bs = b2[c];
#pragma unroll
      for (int i = 0; i < 4; ++i)
        h2[(rl0 + i) * LDH + c] = (__bf16)fmaxf(acc[mt][nt][i] + bs, 0.f);
    }
  }
  __syncthreads();

  f32x4 acc3[2][4];
#pragma unroll
  for (int mt = 0; mt < 2; ++mt)
#pragma unroll
    for (int nt = 0; nt < 4; ++nt) acc3[mt][nt] = (f32x4){0.f, 0.f, 0.f, 0.f};
  bf16x8 a3A[2], a3B[2];
  auto ld3 = [&](int kc, bf16x8 (&av)[2], bf16x8 (&bv)[4]) {
    int ko = kc + quad * 8;
#pragma unroll
    for (int mt = 0; mt < 2; ++mt)
      av[mt] = *(const bf16x8*)&h2[(wave * 32 + mt * 16 + l15) * LDH + ko];
#pragma unroll
    for (int nt = 0; nt < 4; ++nt)
      bv[nt] = *(const bf16x8*)(W3t + (size_t)(nt * 16 + l15) * 128 + ko);
  };
  auto mfma8 = [&](const bf16x8 (&av)[2], const bf16x8 (&bv)[4]) {
#pragma unroll
    for (int mt = 0; mt < 2; ++mt)
#pragma unroll
      for (int nt = 0; nt < 4; ++nt)
        acc3[mt][nt] =
            __builtin_amdgcn_mfma_f32_16x16x32_bf16(av[mt], bv[nt], acc3[mt][nt], 0, 0, 0);
  };
  ld3(0, a3A, bA);
  ld3(32, a3B, bB);
  mfma8(a3A, bA);
  ld3(64, a3A, bA);
  mfma8(a3B, bB);
  ld3(96, a3B, bB);
  mfma8(a3A, bA);
  mfma8(a3B, bB);

  float bcol[4];
#pragma unroll
  for (int nt = 0; nt < 4; ++nt) bcol[nt] = b3[nt * 16 + l15];

#pragma unroll
  for (int mt = 0; mt < 2; ++mt) {
#pragma unroll
    for (int i = 0; i < 4; ++i) {
      int r = rowbase + wave * 32 + mt * 16 + quad * 4 + i;
      float v0 = acc3[mt][0][i] + bcol[0];
      float v1 = acc3[mt][1][i] + bcol[1];
      float v2 = acc3[mt][2][i] + bcol[2];
      float v3 = acc3[mt][3][i] + bcol[3];
      float m = fmaxf(fmaxf(v0, v1), fmaxf(v2, v3));
#pragma unroll
      for (int off = 8; off > 0; off >>= 1) m = fmaxf(m, __shfl_xor(m, off, 16));
      float s = __expf(v0 - m) + __expf(v1 - m) + __expf(v2 - m) + __expf(v3 - m);
#pragma unroll
      for (int off = 8; off > 0; off >>= 1) s += __shfl_xor(s, off, 16);
      float ls = m + __logf(s);
      if (r < M) {
        if (isbf) {
          bf16* op = (bf16*)out + (size_t)r * 64 + l15;
          op[0] = __float2bfloat16(v0 - ls);
          op[16] = __float2bfloat16(v1 - ls);
          op[32] = __float2bfloat16(v2 - ls);
          op[48] = __float2bfloat16(v3 - ls);
        } else {
          float* op = (float*)out + (size_t)r * 64 + l15;
          op[0] = v0 - ls;
          op[16] = v1 - ls;
          op[32] = v2 - ls;
          op[48] = v3 - ls;
        }
      }
    }
  }
}

// ---------- launch ----------

extern "C" void kernel_launch(void* const* d_in, const int* in_sizes, int n_in,
                              void* d_out, int out_size, void* d_ws, size_t ws_size,
                              hipStream_t stream) {
  const void* x = d_in[0];
  const int* ei = (const int*)d_in[1];

  const int N = in_sizes[0] / 512;
  const int E = in_sizes[1] / 2;
  const int* srcp = ei;
  const int* dstp = ei + E;

  char* ws = (char*)d_ws;
  size_t off = 0;
  auto alloc = [&](size_t bytes) {
    void* p = ws + off;
    off = (off + bytes + 255) & ~(size_t)255;
    return p;
  };
  int*    flag    = (int*)alloc(4);
  int*    deg     = (int*)alloc((size_t)N * 4);
  int*    row_ptr = (int*)alloc((size_t)(N + 1) * 4);
  int*    col     = (int*)alloc((size_t)E * 4);
  float*  dinv    = (float*)alloc((size_t)N * 4);
  int*    bsum    = (int*)alloc(1024 * 4);
  __bf16* W0t     = (__bf16*)alloc((size_t)512 * 128 * 2);
  __bf16* W1t     = (__bf16*)alloc((size_t)128 * 128 * 2);
  __bf16* W2t     = (__bf16*)alloc((size_t)128 * 128 * 2);
  __bf16* fc1t    = (__bf16*)alloc((size_t)128 * 128 * 2);
  __bf16* fc2t    = (__bf16*)alloc((size_t)128 * 128 * 2);
  __bf16* fc3t    = (__bf16*)alloc((size_t)64 * 128 * 2);
  float*  b0f     = (float*)alloc(128 * 4);
  float*  b1f     = (float*)alloc(128 * 4);
  float*  b2f     = (float*)alloc(128 * 4);
  float*  fc1bf   = (float*)alloc(128 * 4);
  float*  fc2bf   = (float*)alloc(128 * 4);
  float*  fc3bf   = (float*)alloc(64 * 4);
  bf16*   gbuf    = (bf16*)alloc((size_t)N * 128 * 2);
  bf16*   ybuf    = (bf16*)alloc((size_t)N * 128 * 2);

  const int tb = 256;

  detect_kernel<<<1, 64, 0, stream>>>((const unsigned short*)x, flag);

  CvtAll ca;
  ca.d[0]  = {d_in[2],  W0t,   512 * 128, 512, 128, 1};
  ca.d[1]  = {d_in[4],  W1t,   128 * 128, 128, 128, 1};
  ca.d[2]  = {d_in[6],  W2t,   128 * 128, 128, 128, 1};
  ca.d[3]  = {d_in[8],  fc1t,  128 * 128, 128, 128, 1};
  ca.d[4]  = {d_in[10], fc2t,  128 * 128, 128, 128, 1};
  ca.d[5]  = {d_in[3],  b0f,   128, 0, 0, 0};
  ca.d[6]  = {d_in[5],  b1f,   128, 0, 0, 0};
  ca.d[7]  = {d_in[7],  b2f,   128, 0, 0, 0};
  ca.d[8]  = {d_in[9],  fc1bf, 128, 0, 0, 0};
  ca.d[9]  = {d_in[11], fc2bf, 128, 0, 0, 0};
  ca.d[10] = {d_in[12], fc3t,  128 * 64, 128, 64, 1};
  ca.d[11] = {d_in[13], fc3bf, 64, 0, 0, 0};
  convert_all_kernel<<<dim3(64, 12), 256, 0, stream>>>(ca, flag);

  hipMemsetAsync(deg, 0, (size_t)N * 4, stream);

  count_kernel<<<(E + tb - 1) / tb, tb, 0, stream>>>(dstp, deg, E);
  int nb = (N + 1023) / 1024;
  scan_block_kernel<<<nb, 1024, 0, stream>>>(deg, row_ptr, bsum, dinv, N);
  scan_sums_kernel<<<1, 1024, 0, stream>>>(bsum, nb, row_ptr, N);
  scan_add_kernel<<<(N + tb - 1) / tb, tb, 0, stream>>>(row_ptr, bsum, N);
  fill_kernel<<<(E + tb - 1) / tb, tb, 0, stream>>>(srcp, dstp, row_ptr, deg, col, E);

  int gemm_blocks = (N + 127) / 128;
  int gat_blocks = (N + 3) / 4;

  // conv0 (K=512): contiguous-read persistent kernel, 1 block/CU
  gemm512_contig_kernel<1><<<256, 256, 0, stream>>>(x, W0t, b0f, gbuf, N, dinv, 0, flag);
  gather_kernel<<<gat_blocks, 256, 0, stream>>>(gbuf, row_ptr, col, dinv, ybuf, N);
  // conv1 (K=128): round-8 staged structure
  gemm_mfma_kernel<128, 0><<<gemm_blocks, 256, 0, stream>>>(ybuf, W1t, b1f, gbuf, N, dinv, 0, flag);
  gather_kernel<<<gat_blocks, 256, 0, stream>>>(gbuf, row_ptr, col, dinv, ybuf, N);
  // conv2 (K=128): round-8 staged structure
  gemm_mfma_kernel<128, 0><<<gemm_blocks, 256, 0, stream>>>(ybuf, W2t, b2f, gbuf, N, dinv, 0, flag);
  gather_kernel<<<gat_blocks, 256, 0, stream>>>(gbuf, row_ptr, col, dinv, ybuf, N);
  // fused fc1+fc2+fc3+log_softmax
  fc_chain_kernel<<<gemm_blocks, 256, 0, stream>>>(ybuf, fc1t, fc1bf, fc2t, fc2bf,
                                                   fc3t, fc3bf, d_out, N, flag);
}

// Round 11
// 778.943 us; speedup vs baseline: 1.0872x; 1.0872x over previous
//
#include <hip/hip_runtime.h>
#include <hip/hip_bf16.h>
#include <cstdint>

typedef __hip_bfloat16 bf16;
typedef __hip_bfloat162 bf162;
typedef __bf16 bf16x8 __attribute__((ext_vector_type(8)));
typedef float f32x4 __attribute__((ext_vector_type(4)));

// ---------- dtype detection ----------
__global__ void detect_kernel(const unsigned short* __restrict__ xr, int* __restrict__ flag) {
  if (threadIdx.x == 0 && blockIdx.x == 0) {
    int pass = 0;
    for (int i = 0; i < 64; ++i) {
      unsigned short h = xr[2 * i];
      int e = (h >> 7) & 0xFF;
      if (e >= 110 && e <= 140) pass++;
    }
    *flag = (pass >= 32) ? 1 : 0;
  }
}

// ---------- batched weight conversion: 12 tensors in one launch ----------
struct CvtDesc {
  const void* src;
  void* dst;
  int n, fi, fo, mode;  // mode 1: transpose [fi][fo] -> bf16 [fo][fi]; mode 0: flat fp32
};
struct CvtAll { CvtDesc d[12]; };

__global__ void convert_all_kernel(CvtAll all, const int* __restrict__ flag) {
  CvtDesc dd = all.d[blockIdx.y];
  int isbf = *flag;
  for (int i = blockIdx.x * blockDim.x + threadIdx.x; i < dd.n; i += gridDim.x * blockDim.x) {
    float v = isbf ? __bfloat162float(((const bf16*)dd.src)[i]) : ((const float*)dd.src)[i];
    if (dd.mode) {
      int k = i / dd.fo, nn = i - k * dd.fo;
      ((__bf16*)dd.dst)[(size_t)nn * dd.fi + k] = (__bf16)v;
    } else {
      ((float*)dd.dst)[i] = v;
    }
  }
}

// ---------- graph preprocessing ----------

__global__ void count_kernel(const int* __restrict__ dst, int* __restrict__ deg, int E) {
  int i = blockIdx.x * blockDim.x + threadIdx.x;
  if (i < E) atomicAdd(&deg[dst[i]], 1);
}

// scan_block also emits dinv = rsqrt(deg+1) (it reads deg anyway; saves a launch)
__global__ void scan_block_kernel(const int* __restrict__ counts, int* __restrict__ excl,
                                  int* __restrict__ bsum, float* __restrict__ dinv, int n) {
  __shared__ int sd[1024];
  int t = threadIdx.x;
  int i = blockIdx.x * 1024 + t;
  int v = (i < n) ? counts[i] : 0;
  if (i < n) dinv[i] = rsqrtf((float)(v + 1));  // +1 self-loop
  sd[t] = v;
  __syncthreads();
  for (int off = 1; off < 1024; off <<= 1) {
    int x = (t >= off) ? sd[t - off] : 0;
    __syncthreads();
    sd[t] += x;
    __syncthreads();
  }
  if (i < n) excl[i] = sd[t] - v;
  if (t == 1023) bsum[blockIdx.x] = sd[1023];
}

__global__ void scan_sums_kernel(int* __restrict__ bsum, int nb, int* __restrict__ row_ptr, int n) {
  __shared__ int sd[1024];
  int t = threadIdx.x;
  int v = (t < nb) ? bsum[t] : 0;
  sd[t] = v;
  __syncthreads();
  for (int off = 1; off < 1024; off <<= 1) {
    int x = (t >= off) ? sd[t - off] : 0;
    __syncthreads();
    sd[t] += x;
    __syncthreads();
  }
  if (t < nb) bsum[t] = sd[t] - v;
  if (t == 1023) row_ptr[n] = sd[1023];
}

__global__ void scan_add_kernel(int* __restrict__ excl, const int* __restrict__ bsum, int n) {
  int i = blockIdx.x * blockDim.x + threadIdx.x;
  if (i < n) excl[i] += bsum[i >> 10];
}

// ---------- async global->LDS helper (16B, literal size per guide) ----------
__device__ __forceinline__ void gload_lds16(const void* g, void* l) {
  __builtin_amdgcn_global_load_lds(
      (const __attribute__((address_space(1))) void*)g,
      (__attribute__((address_space(3))) void*)l, 16, 0, 0);
}

// ---------- FUSED conv0 GEMM + CSR fill (round-11) ----------
// Round-10 postmortem: contiguity theory falsified (160us, worse). Round-8
// counted-vmcnt structure (119us) is the measured optimum for the GEMM; the
// ~1 TB/s read wall held across 4 different structures -> stop fighting it
// per-kernel. New lever: fill_kernel (131us, 16x write amplification,
// algorithmically irreducible scatter) and conv0 are INDEPENDENT in the DAG
// but serialize on the stream (~250us combined). This kernel runs both in
// ONE launch with parity-interleaved roles: even blocks = round-8 GEMM
// verbatim, odd blocks = grid-stride fill scatter. Interleaving gives every
// CU one of each from t=0, overlapping the ~900GB/s read stream with the
// ~900GB/s scatter-write stream (fabric sustains 6.9TB/s). Fill blocks
// return before any barrier (block-uniform -> no divergent-barrier hazard).
// GEMM body: A+B DMA-staged, T4 counted vmcnt(8), raw barriers,
// sched_barrier fences (rule #18); XOR swizzle slot^(row&7) pre-swizzled
// on GLOBAL source + swizzled read, LDS dest linear (rule #21).
// Wave: 64x64 via 4x4 of 16x16x32 MFMA; C/D col=lane&15, row=quad*4+reg.

template <int K, int ADUAL>
__global__ __launch_bounds__(256) void gemm_fill_kernel(
    const void* __restrict__ Ain, const __bf16* __restrict__ Bt,
    const float* __restrict__ bias, bf16* __restrict__ C,
    int M, const float* __restrict__ rowscale, int do_relu,
    const int* __restrict__ flag,
    const int* __restrict__ srcp, const int* __restrict__ dstp,
    const int* __restrict__ row_ptr, int* __restrict__ deg,
    int* __restrict__ col, int E) {
  constexpr int BK = 64;
  constexpr int NT = K / BK;
  __shared__ __align__(16) __bf16 As[2][128 * BK];
  __shared__ __align__(16) __bf16 Bs[2][128 * BK];

  int bid = blockIdx.x >> 1;
  if (blockIdx.x & 1) {
    // ---- fill role: grid-stride CSR scatter (same semantics as before) ----
    int nfb = gridDim.x >> 1;
    for (int i = bid * 256 + (int)threadIdx.x; i < E; i += nfb * 256) {
      int d = dstp[i];
      int k = atomicSub(&deg[d], 1) - 1;
      col[row_ptr[d] + k] = srcp[i];
    }
    return;  // before any barrier; block-uniform
  }

  // ---- GEMM role (round-8 measured-best body, rowbase from bid) ----
  const int abf = ADUAL ? flag[0] : 1;
  int t = threadIdx.x;
  int wave = t >> 6, lane = t & 63;
  int l15 = lane & 15, quad = lane >> 4;
  int wm = wave >> 1, wn = wave & 1;
  int rowbase = bid * 128;
  const __bf16* Ab = (const __bf16*)Ain;
  const float* Af = (const float*)Ain;

  int srow = t >> 3;
  int sslot = t & 7;
  int xslot = sslot ^ (srow & 7);

  int sArow[4];
#pragma unroll
  for (int i = 0; i < 4; ++i) {
    int r = rowbase + i * 32 + srow;
    sArow[i] = (r < M) ? r : (M - 1);
  }

  f32x4 acc[4][4];
#pragma unroll
  for (int mt = 0; mt < 4; ++mt)
#pragma unroll
    for (int nt = 0; nt < 4; ++nt) acc[mt][nt] = (f32x4){0.f, 0.f, 0.f, 0.f};

  auto stage = [&](int kt, int buf) {
    int kbase = kt * BK + xslot * 8;
    if (abf) {
#pragma unroll
      for (int i = 0; i < 4; ++i)
        gload_lds16(Ab + (size_t)sArow[i] * K + kbase, &As[buf][t * 8 + i * 2048]);
    } else {
#pragma unroll
      for (int i = 0; i < 4; ++i) {
        const float* p = Af + (size_t)sArow[i] * K + kbase;
        bf16x8 v;
#pragma unroll
        for (int j = 0; j < 8; ++j) v[j] = (__bf16)p[j];
        *(bf16x8*)&As[buf][t * 8 + i * 2048] = v;
      }
    }
#pragma unroll
    for (int i = 0; i < 4; ++i)
      gload_lds16(Bt + (size_t)(i * 32 + srow) * K + kbase, &Bs[buf][t * 8 + i * 2048]);
  };

  auto compute = [&](int buf) {
#pragma unroll
    for (int c = 0; c < 2; ++c) {
      bf16x8 av[4], bv[4];
#pragma unroll
      for (int mt = 0; mt < 4; ++mt) {
        int row = wm * 64 + mt * 16 + l15;
        int slot = (c * 4 + quad) ^ (row & 7);
        av[mt] = *(const bf16x8*)&As[buf][row * BK + slot * 8];
      }
#pragma unroll
      for (int nt = 0; nt < 4; ++nt) {
        int row = wn * 64 + nt * 16 + l15;
        int slot = (c * 4 + quad) ^ (row & 7);
        bv[nt] = *(const bf16x8*)&Bs[buf][row * BK + slot * 8];
      }
#pragma unroll
      for (int mt = 0; mt < 4; ++mt)
#pragma unroll
        for (int nt = 0; nt < 4; ++nt)
          acc[mt][nt] =
              __builtin_amdgcn_mfma_f32_16x16x32_bf16(av[mt], bv[nt], acc[mt][nt], 0, 0, 0);
    }
  };

  stage(0, 0);
  if (abf) {
#pragma unroll
    for (int kt = 0; kt < NT; ++kt) {
      int cur = kt & 1;
      if (kt + 1 < NT) {
        stage(kt + 1, cur ^ 1);
        asm volatile("s_waitcnt vmcnt(8)" ::: "memory");
      } else {
        asm volatile("s_waitcnt vmcnt(0)" ::: "memory");
      }
      __builtin_amdgcn_sched_barrier(0);
      __builtin_amdgcn_s_barrier();
      __builtin_amdgcn_sched_barrier(0);
      compute(cur);
      __builtin_amdgcn_sched_barrier(0);
      __builtin_amdgcn_s_barrier();
    }
  } else {
    __syncthreads();
#pragma unroll
    for (int kt = 0; kt < NT; ++kt) {
      int cur = kt & 1;
      if (kt + 1 < NT) stage(kt + 1, cur ^ 1);
      compute(cur);
      __syncthreads();
    }
  }

#pragma unroll
  for (int mt = 0; mt < 4; ++mt) {
    int r0 = rowbase + wm * 64 + mt * 16 + quad * 4;
#pragma unroll
    for (int nt = 0; nt < 4; ++nt) {
      int c = wn * 64 + nt * 16 + l15;
      float bs = bias[c];
#pragma unroll
      for (int i = 0; i < 4; ++i) {
        int r = r0 + i;
        if (r < M) {
          float v = acc[mt][nt][i] + bs;
          if (rowscale) v *= rowscale[r];
          if (do_relu) v = fmaxf(v, 0.f);
          C[(size_t)r * 128 + c] = __float2bfloat16(v);
        }
      }
    }
  }
}

// ---------- MFMA GEMM (K=128): round-8 proven A+B LDS staging, counted vmcnt ----------

template <int K, int ADUAL>
__global__ __launch_bounds__(256) void gemm_mfma_kernel(
    const void* __restrict__ Ain, const __bf16* __restrict__ Bt,
    const float* __restrict__ bias, bf16* __restrict__ C,
    int M, const float* __restrict__ rowscale, int do_relu,
    const int* __restrict__ flag) {
  constexpr int BK = 64;
  constexpr int NT = K / BK;
  __shared__ __align__(16) __bf16 As[2][128 * BK];
  __shared__ __align__(16) __bf16 Bs[2][128 * BK];

  const int abf = ADUAL ? flag[0] : 1;
  int t = threadIdx.x;
  int wave = t >> 6, lane = t & 63;
  int l15 = lane & 15, quad = lane >> 4;
  int wm = wave >> 1, wn = wave & 1;
  int rowbase = blockIdx.x * 128;
  const __bf16* Ab = (const __bf16*)Ain;
  const float* Af = (const float*)Ain;

  int srow = t >> 3;
  int sslot = t & 7;
  int xslot = sslot ^ (srow & 7);

  int sArow[4];
#pragma unroll
  for (int i = 0; i < 4; ++i) {
    int r = rowbase + i * 32 + srow;
    sArow[i] = (r < M) ? r : (M - 1);
  }

  f32x4 acc[4][4];
#pragma unroll
  for (int mt = 0; mt < 4; ++mt)
#pragma unroll
    for (int nt = 0; nt < 4; ++nt) acc[mt][nt] = (f32x4){0.f, 0.f, 0.f, 0.f};

  auto stage = [&](int kt, int buf) {
    int kbase = kt * BK + xslot * 8;
    if (abf) {
#pragma unroll
      for (int i = 0; i < 4; ++i)
        gload_lds16(Ab + (size_t)sArow[i] * K + kbase, &As[buf][t * 8 + i * 2048]);
    } else {
#pragma unroll
      for (int i = 0; i < 4; ++i) {
        const float* p = Af + (size_t)sArow[i] * K + kbase;
        bf16x8 v;
#pragma unroll
        for (int j = 0; j < 8; ++j) v[j] = (__bf16)p[j];
        *(bf16x8*)&As[buf][t * 8 + i * 2048] = v;
      }
    }
#pragma unroll
    for (int i = 0; i < 4; ++i)
      gload_lds16(Bt + (size_t)(i * 32 + srow) * K + kbase, &Bs[buf][t * 8 + i * 2048]);
  };

  auto compute = [&](int buf) {
#pragma unroll
    for (int c = 0; c < 2; ++c) {
      bf16x8 av[4], bv[4];
#pragma unroll
      for (int mt = 0; mt < 4; ++mt) {
        int row = wm * 64 + mt * 16 + l15;
        int slot = (c * 4 + quad) ^ (row & 7);
        av[mt] = *(const bf16x8*)&As[buf][row * BK + slot * 8];
      }
#pragma unroll
      for (int nt = 0; nt < 4; ++nt) {
        int row = wn * 64 + nt * 16 + l15;
        int slot = (c * 4 + quad) ^ (row & 7);
        bv[nt] = *(const bf16x8*)&Bs[buf][row * BK + slot * 8];
      }
#pragma unroll
      for (int mt = 0; mt < 4; ++mt)
#pragma unroll
        for (int nt = 0; nt < 4; ++nt)
          acc[mt][nt] =
              __builtin_amdgcn_mfma_f32_16x16x32_bf16(av[mt], bv[nt], acc[mt][nt], 0, 0, 0);
    }
  };

  stage(0, 0);
  if (abf) {
#pragma unroll
    for (int kt = 0; kt < NT; ++kt) {
      int cur = kt & 1;
      if (kt + 1 < NT) {
        stage(kt + 1, cur ^ 1);
        asm volatile("s_waitcnt vmcnt(8)" ::: "memory");
      } else {
        asm volatile("s_waitcnt vmcnt(0)" ::: "memory");
      }
      __builtin_amdgcn_sched_barrier(0);
      __builtin_amdgcn_s_barrier();
      __builtin_amdgcn_sched_barrier(0);
      compute(cur);
      __builtin_amdgcn_sched_barrier(0);
      __builtin_amdgcn_s_barrier();
    }
  } else {
    __syncthreads();
#pragma unroll
    for (int kt = 0; kt < NT; ++kt) {
      int cur = kt & 1;
      if (kt + 1 < NT) stage(kt + 1, cur ^ 1);
      compute(cur);
      __syncthreads();
    }
  }

#pragma unroll
  for (int mt = 0; mt < 4; ++mt) {
    int r0 = rowbase + wm * 64 + mt * 16 + quad * 4;
#pragma unroll
    for (int nt = 0; nt < 4; ++nt) {
      int c = wn * 64 + nt * 16 + l15;
      float bs = bias[c];
#pragma unroll
      for (int i = 0; i < 4; ++i) {
        int r = r0 + i;
        if (r < M) {
          float v = acc[mt][nt][i] + bs;
          if (rowscale) v *= rowscale[r];
          if (do_relu) v = fmaxf(v, 0.f);
          C[(size_t)r * 128 + c] = __float2bfloat16(v);
        }
      }
    }
  }
}

// ---------- gather: y[d] = relu(dinv[d]*(g[d] + sum_{s in CSR[d]} g[s])) ----------
// 8-wide batches + next-batch col prefetch; round-7 showed fabric/BW-bound
// (~3 TB/s random 256B from L3). Best measured variant; unchanged.

__global__ __launch_bounds__(256) void gather_kernel(
    const bf16* __restrict__ g, const int* __restrict__ row_ptr, const int* __restrict__ col,
    const float* __restrict__ dinv, bf16* __restrict__ y, int n) {
  int wave = threadIdx.x >> 6;
  int lane = threadIdx.x & 63;
  int node = blockIdx.x * 4 + wave;
  if (node >= n) return;
  const bf162* gp = (const bf162*)g;
  bf162 sv = gp[(size_t)node * 64 + lane];
  float ax = __bfloat162float(sv.x), ay = __bfloat162float(sv.y);
  float bx = 0.f, by = 0.f;
  int beg = row_ptr[node], end = row_ptr[node + 1];

  if (beg < end) {
    int sc[8], sn[8];
    float mc[8], mn[8];
#pragma unroll
    for (int j = 0; j < 8; ++j) {
      int ee = beg + j;
      bool ok = ee < end;
      sc[j] = col[ok ? ee : beg];
      mc[j] = ok ? 1.f : 0.f;
    }
    for (int e = beg; e < end; e += 8) {
      bf162 v[8];
#pragma unroll
      for (int j = 0; j < 8; ++j) v[j] = gp[(size_t)sc[j] * 64 + lane];
      int e2 = e + 8;
      bool more = e2 < end;
      if (more) {
#pragma unroll
        for (int j = 0; j < 8; ++j) {
          int ee = e2 + j;
          bool ok = ee < end;
          sn[j] = col[ok ? ee : beg];
          mn[j] = ok ? 1.f : 0.f;
        }
      }
#pragma unroll
      for (int j = 0; j < 8; j += 2) {
        ax = fmaf(mc[j], __bfloat162float(v[j].x), ax);
        ay = fmaf(mc[j], __bfloat162float(v[j].y), ay);
        bx = fmaf(mc[j + 1], __bfloat162float(v[j + 1].x), bx);
        by = fmaf(mc[j + 1], __bfloat162float(v[j + 1].y), by);
      }
      if (more) {
#pragma unroll
        for (int j = 0; j < 8; ++j) {
          sc[j] = sn[j];
          mc[j] = mn[j];
        }
      }
    }
  }
  float dv = dinv[node];
  float ox = fmaxf((ax + bx) * dv, 0.f);
  float oy = fmaxf((ay + by) * dv, 0.f);
  bf162 o;
  o.x = __float2bfloat16(ox);
  o.y = __float2bfloat16(oy);
  ((bf162*)y)[(size_t)node * 64 + lane] = o;
}

// ---------- fused FC chain: out = log_softmax(relu(relu(y@W1+b1)@W2+b2)@W3+b3) ----------

__global__ __launch_bounds__(256) void fc_chain_kernel(
    const bf16* __restrict__ yin, const __bf16* __restrict__ W1t,
    const float* __restrict__ b1, const __bf16* __restrict__ W2t,
    const float* __restrict__ b2, const __bf16* __restrict__ W3t,
    const float* __restrict__ b3, void* __restrict__ out, int M,
    const int* __restrict__ flag) {
  constexpr int LDH = 136;
  __shared__ __align__(16) __bf16 h1[128 * LDH];
  __shared__ __align__(16) __bf16 h2[128 * LDH];
  const int isbf = flag[0];
  int t = threadIdx.x;
  int wave = t >> 6, lane = t & 63;
  int l15 = lane & 15, quad = lane >> 4;
  int wm = wave >> 1, wn = wave & 1;
  int rowbase = blockIdx.x * 128;

  f32x4 acc[4][4];
  bf16x8 aA[4], bA[4], aB[4], bB[4];

  auto zacc = [&]() {
#pragma unroll
    for (int mt = 0; mt < 4; ++mt)
#pragma unroll
      for (int nt = 0; nt < 4; ++nt) acc[mt][nt] = (f32x4){0.f, 0.f, 0.f, 0.f};
  };
  auto mfma16 = [&](const bf16x8 (&av)[4], const bf16x8 (&bv)[4]) {
#pragma unroll
    for (int mt = 0; mt < 4; ++mt)
#pragma unroll
      for (int nt = 0; nt < 4; ++nt)
        acc[mt][nt] =
            __builtin_amdgcn_mfma_f32_16x16x32_bf16(av[mt], bv[nt], acc[mt][nt], 0, 0, 0);
  };

  int arow[4];
#pragma unroll
  for (int mt = 0; mt < 4; ++mt) {
    int r = rowbase + wm * 64 + mt * 16 + l15;
    arow[mt] = (r < M) ? r : (M - 1);
  }
  auto ld1 = [&](int kc, bf16x8 (&av)[4], bf16x8 (&bv)[4]) {
    int ko = kc + quad * 8;
#pragma unroll
    for (int mt = 0; mt < 4; ++mt)
      av[mt] = *(const bf16x8*)(yin + (size_t)arow[mt] * 128 + ko);
#pragma unroll
    for (int nt = 0; nt < 4; ++nt)
      bv[nt] = *(const bf16x8*)(W1t + (size_t)(wn * 64 + nt * 16 + l15) * 128 + ko);
  };
  zacc();
  ld1(0, aA, bA);
  ld1(32, aB, bB);
  mfma16(aA, bA);
  ld1(64, aA, bA);
  mfma16(aB, bB);
  ld1(96, aB, bB);
  mfma16(aA, bA);
  mfma16(aB, bB);
#pragma unroll
  for (int mt = 0; mt < 4; ++mt) {
    int rl0 = wm * 64 + mt * 16 + quad * 4;
#pragma unroll
    for (int nt = 0; nt < 4; ++nt) {
      int c = wn * 64 + nt * 16 + l15;
      float bs = b1[c];
#pragma unroll
      for (int i = 0; i < 4; ++i)
        h1[(rl0 + i) * LDH + c] = (__bf16)fmaxf(acc[mt][nt][i] + bs, 0.f);
    }
  }
  __syncthreads();

  auto ld2 = [&](int kc, bf16x8 (&av)[4], bf16x8 (&bv)[4]) {
    int ko = kc + quad * 8;
#pragma unroll
    for (int mt = 0; mt < 4; ++mt)
      av[mt] = *(const bf16x8*)&h1[(wm * 64 + mt * 16 + l15) * LDH + ko];
#pragma unroll
    for (int nt = 0; nt < 4; ++nt)
      bv[nt] = *(const bf16x8*)(W2t + (size_t)(wn * 64 + nt * 16 + l15) * 128 + ko);
  };
  zacc();
  ld2(0, aA, bA);
  ld2(32, aB, bB);
  mfma16(aA, bA);
  ld2(64, aA, bA);
  mfma16(aB, bB);
  ld2(96, aB, bB);
  mfma16(aA, bA);
  mfma16(aB, bB);
#pragma unroll
  for (int mt = 0; mt < 4; ++mt) {
    int rl0 = wm * 64 + mt * 16 + quad * 4;
#pragma unroll
    for (int nt = 0; nt < 4; ++nt) {
      int c = wn * 64 + nt * 16 + l15;
      float bs = b2[c];
#pragma unroll
      for (int i = 0; i < 4; ++i)
        h2[(rl0 + i) * LDH + c] = (__bf16)fmaxf(acc[mt][nt][i] + bs, 0.f);
    }
  }
  __syncthreads();

  f32x4 acc3[2][4];
#pragma unroll
  for (int mt = 0; mt < 2; ++mt)
#pragma unroll
    for (int nt = 0; nt < 4; ++nt) acc3[mt][nt] = (f32x4){0.f, 0.f, 0.f, 0.f};
  bf16x8 a3A[2], a3B[2];
  auto ld3 = [&](int kc, bf16x8 (&av)[2], bf16x8 (&bv)[4]) {
    int ko = kc + quad * 8;
#pragma unroll
    for (int mt = 0; mt < 2; ++mt)
      av[mt] = *(const bf16x8*)&h2[(wave * 32 + mt * 16 + l15) * LDH + ko];
#pragma unroll
    for (int nt = 0; nt < 4; ++nt)
      bv[nt] = *(const bf16x8*)(W3t + (size_t)(nt * 16 + l15) * 128 + ko);
  };
  auto mfma8 = [&](const bf16x8 (&av)[2], const bf16x8 (&bv)[4]) {
#pragma unroll
    for (int mt = 0; mt < 2; ++mt)
#pragma unroll
      for (int nt = 0; nt < 4; ++nt)
        acc3[mt][nt] =
            __builtin_amdgcn_mfma_f32_16x16x32_bf16(av[mt], bv[nt], acc3[mt][nt], 0, 0, 0);
  };
  ld3(0, a3A, bA);
  ld3(32, a3B, bB);
  mfma8(a3A, bA);
  ld3(64, a3A, bA);
  mfma8(a3B, bB);
  ld3(96, a3B, bB);
  mfma8(a3A, bA);
  mfma8(a3B, bB);

  float bcol[4];
#pragma unroll
  for (int nt = 0; nt < 4; ++nt) bcol[nt] = b3[nt * 16 + l15];

#pragma unroll
  for (int mt = 0; mt < 2; ++mt) {
#pragma unroll
    for (int i = 0; i < 4; ++i) {
      int r = rowbase + wave * 32 + mt * 16 + quad * 4 + i;
      float v0 = acc3[mt][0][i] + bcol[0];
      float v1 = acc3[mt][1][i] + bcol[1];
      float v2 = acc3[mt][2][i] + bcol[2];
      float v3 = acc3[mt][3][i] + bcol[3];
      float m = fmaxf(fmaxf(v0, v1), fmaxf(v2, v3));
#pragma unroll
      for (int off = 8; off > 0; off >>= 1) m = fmaxf(m, __shfl_xor(m, off, 16));
      float s = __expf(v0 - m) + __expf(v1 - m) + __expf(v2 - m) + __expf(v3 - m);
#pragma unroll
      for (int off = 8; off > 0; off >>= 1) s += __shfl_xor(s, off, 16);
      float ls = m + __logf(s);
      if (r < M) {
        if (isbf) {
          bf16* op = (bf16*)out + (size_t)r * 64 + l15;
          op[0] = __float2bfloat16(v0 - ls);
          op[16] = __float2bfloat16(v1 - ls);
          op[32] = __float2bfloat16(v2 - ls);
          op[48] = __float2bfloat16(v3 - ls);
        } else {
          float* op = (float*)out + (size_t)r * 64 + l15;
          op[0] = v0 - ls;
          op[16] = v1 - ls;
          op[32] = v2 - ls;
          op[48] = v3 - ls;
        }
      }
    }
  }
}

// ---------- launch ----------

extern "C" void kernel_launch(void* const* d_in, const int* in_sizes, int n_in,
                              void* d_out, int out_size, void* d_ws, size_t ws_size,
                              hipStream_t stream) {
  const void* x = d_in[0];
  const int* ei = (const int*)d_in[1];

  const int N = in_sizes[0] / 512;
  const int E = in_sizes[1] / 2;
  const int* srcp = ei;
  const int* dstp = ei + E;

  char* ws = (char*)d_ws;
  size_t off = 0;
  auto alloc = [&](size_t bytes) {
    void* p = ws + off;
    off = (off + bytes + 255) & ~(size_t)255;
    return p;
  };
  int*    flag    = (int*)alloc(4);
  int*    deg     = (int*)alloc((size_t)N * 4);
  int*    row_ptr = (int*)alloc((size_t)(N + 1) * 4);
  int*    col     = (int*)alloc((size_t)E * 4);
  float*  dinv    = (float*)alloc((size_t)N * 4);
  int*    bsum    = (int*)alloc(1024 * 4);
  __bf16* W0t     = (__bf16*)alloc((size_t)512 * 128 * 2);
  __bf16* W1t     = (__bf16*)alloc((size_t)128 * 128 * 2);
  __bf16* W2t     = (__bf16*)alloc((size_t)128 * 128 * 2);
  __bf16* fc1t    = (__bf16*)alloc((size_t)128 * 128 * 2);
  __bf16* fc2t    = (__bf16*)alloc((size_t)128 * 128 * 2);
  __bf16* fc3t    = (__bf16*)alloc((size_t)64 * 128 * 2);
  float*  b0f     = (float*)alloc(128 * 4);
  float*  b1f     = (float*)alloc(128 * 4);
  float*  b2f     = (float*)alloc(128 * 4);
  float*  fc1bf   = (float*)alloc(128 * 4);
  float*  fc2bf   = (float*)alloc(128 * 4);
  float*  fc3bf   = (float*)alloc(64 * 4);
  bf16*   gbuf    = (bf16*)alloc((size_t)N * 128 * 2);
  bf16*   ybuf    = (bf16*)alloc((size_t)N * 128 * 2);

  const int tb = 256;

  detect_kernel<<<1, 64, 0, stream>>>((const unsigned short*)x, flag);

  CvtAll ca;
  ca.d[0]  = {d_in[2],  W0t,   512 * 128, 512, 128, 1};
  ca.d[1]  = {d_in[4],  W1t,   128 * 128, 128, 128, 1};
  ca.d[2]  = {d_in[6],  W2t,   128 * 128, 128, 128, 1};
  ca.d[3]  = {d_in[8],  fc1t,  128 * 128, 128, 128, 1};
  ca.d[4]  = {d_in[10], fc2t,  128 * 128, 128, 128, 1};
  ca.d[5]  = {d_in[3],  b0f,   128, 0, 0, 0};
  ca.d[6]  = {d_in[5],  b1f,   128, 0, 0, 0};
  ca.d[7]  = {d_in[7],  b2f,   128, 0, 0, 0};
  ca.d[8]  = {d_in[9],  fc1bf, 128, 0, 0, 0};
  ca.d[9]  = {d_in[11], fc2bf, 128, 0, 0, 0};
  ca.d[10] = {d_in[12], fc3t,  128 * 64, 128, 64, 1};
  ca.d[11] = {d_in[13], fc3bf, 64, 0, 0, 0};
  convert_all_kernel<<<dim3(64, 12), 256, 0, stream>>>(ca, flag);

  hipMemsetAsync(deg, 0, (size_t)N * 4, stream);

  count_kernel<<<(E + tb - 1) / tb, tb, 0, stream>>>(dstp, deg, E);
  int nb = (N + 1023) / 1024;
  scan_block_kernel<<<nb, 1024, 0, stream>>>(deg, row_ptr, bsum, dinv, N);
  scan_sums_kernel<<<1, 1024, 0, stream>>>(bsum, nb, row_ptr, N);
  scan_add_kernel<<<(N + tb - 1) / tb, tb, 0, stream>>>(row_ptr, bsum, N);

  int gemm_blocks = (N + 127) / 128;
  int gat_blocks = (N + 3) / 4;

  // conv0 GEMM fused with CSR fill (independent DAG nodes -> one launch,
  // parity-interleaved roles overlap the read and scatter-write streams)
  gemm_fill_kernel<512, 1><<<2 * gemm_blocks, 256, 0, stream>>>(
      x, W0t, b0f, gbuf, N, dinv, 0, flag, srcp, dstp, row_ptr, deg, col, E);
  gather_kernel<<<gat_blocks, 256, 0, stream>>>(gbuf, row_ptr, col, dinv, ybuf, N);
  // conv1
  gemm_mfma_kernel<128, 0><<<gemm_blocks, 256, 0, stream>>>(ybuf, W1t, b1f, gbuf, N, dinv, 0, flag);
  gather_kernel<<<gat_blocks, 256, 0, stream>>>(gbuf, row_ptr, col, dinv, ybuf, N);
  // conv2
  gemm_mfma_kernel<128, 0><<<gemm_blocks, 256, 0, stream>>>(ybuf, W2t, b2f, gbuf, N, dinv, 0, flag);
  gather_kernel<<<gat_blocks, 256, 0, stream>>>(gbuf, row_ptr, col, dinv, ybuf, N);
  // fused fc1+fc2+fc3+log_softmax
  fc_chain_kernel<<<gemm_blocks, 256, 0, stream>>>(ybuf, fc1t, fc1bf, fc2t, fc2bf,
                                                   fc3t, fc3bf, d_out, N, flag);
}